// Round 5
// baseline (256.341 us; speedup 1.0000x reference)
//
#include <hip/hip_runtime.h>
#include <hip/hip_bf16.h>

// ---------------------------------------------------------------------------
// HybridAutoEncoder on MI355X — bf16 MFMA, B-direct (LDS-bypass) GEMM.
//
// LDS-BW analysis (R4): both-operand LDS staging moves 2.4 GB/GEMM through
// LDS (69 TB/s ceiling -> 35 us floor; measured 43 = 81%). Fix: B operand
// loaded global->VGPR directly in MFMA fragment layout (16B/lane along K,
// lanes lh=0..3 consume full 64B lines; weights are L2-resident), A staged
// via swizzled global_load_lds into a 3-buffer ring (depth-2 prefetch,
// counted vmcnt). Big BM amortizes B L2 traffic. All grids = 256 wgs
// (1 block/CU, 4 waves); XCD-swizzle keeps each XCD's B-panels L2-resident.
//
//   enc1: relu(x@W1^T+b1)    gemm_bdir<128,128>  grid 256  K=4096
//   enc2: relu(h1@W2^T+b2)   gemm_bdir<128,64>   grid 256  K=2048  (f32 out)
//   enc3+quantum+dec1 fused  (analytic quantum latent)
//   dec2: relu(h3@dW2^T+db2) gemm_bdir<256,64>   grid 256  K=1024
//   dec3: h4@dW3^T+db3       gemm_bdir<256,128>  grid 256  K=2048  (f32 out)
// ---------------------------------------------------------------------------

typedef __bf16 bf16x8 __attribute__((ext_vector_type(8)));
typedef __bf16 bf16x4 __attribute__((ext_vector_type(4)));
typedef float  f32x4  __attribute__((ext_vector_type(4)));

__device__ __forceinline__ void async16(const void* g, void* l) {
    __builtin_amdgcn_global_load_lds(
        (const __attribute__((address_space(1))) unsigned int*)g,
        (__attribute__((address_space(3))) unsigned int*)l,
        16, 0, 0);
}

template<int VM> __device__ __forceinline__ void wait_vm_lgkm0() {
    if constexpr (VM == 0)      asm volatile("s_waitcnt vmcnt(0) lgkmcnt(0)" ::: "memory");
    else if constexpr (VM == 4) asm volatile("s_waitcnt vmcnt(4) lgkmcnt(0)" ::: "memory");
    else if constexpr (VM == 8) asm volatile("s_waitcnt vmcnt(8) lgkmcnt(0)" ::: "memory");
    else static_assert(VM == 0 || VM == 4 || VM == 8, "unsupported VM");
}

// C = act(A @ W^T + bias). A: MxK bf16 row-major (LDS-staged, swizzled).
// W: NxK bf16 row-major (direct global->reg in fragment layout).
// K mult of 128 (NT even, >=4). Grid (N/BN, M/BM), product mult of 8.
// Dynamic LDS = 3*BM*128 bytes.
template <int BM, int BN, typename TOUT, bool RELU>
__global__ __launch_bounds__(256) void gemm_bdir(
    const __bf16* __restrict__ A, const __bf16* __restrict__ W,
    const float* __restrict__ bias, TOUT* __restrict__ C,
    int M, int N, int K)
{
    constexpr int CHA = BM / 32;              // gload_lds per wave per stage
    constexpr int WMR = BM / 2, WNC = BN / 2; // wave tile (2x2 waves)
    constexpr int NI = WMR / 16, NJ = WNC / 16;
    constexpr int ABYTES = BM * 128;

    extern __shared__ char smem[];

    const int t = threadIdx.x, lane = t & 63, w = t >> 6;

    // XCD-aware bijective block swizzle; column-major decode so each XCD
    // owns a few bn-panels (B stays L2-resident per XCD).
    const int gx = gridDim.x, gy = gridDim.y;
    const int lin = blockIdx.y * gx + blockIdx.x;
    const int cpx = (gx * gy) >> 3;
    const int swz = (lin & 7) * cpx + (lin >> 3);
    const int bm = (swz % gy) * BM;
    const int bn = (swz / gy) * BN;

    // A staging: 8 lanes/row, XOR-swizzled source col-slot (both-sides rule)
    const int sr  = lane >> 3;
    const int scs = (lane & 7) ^ sr;
    const __bf16* gA = A + (size_t)(bm + w * 8 + sr) * K + scs * 8;

    // fragment decomposition
    const int lm = lane & 15, lh = lane >> 4;
    const int wm = w >> 1, wn = w & 1;
    const int axor = lm & 7;

    // B direct: lane base; frag (kh,j) at chunk tt = gB + j*16*K + tt*64 + kh*32
    const __bf16* gB = W + (size_t)(bn + wn * WNC + lm) * K + lh * 8;

    f32x4 acc[NI][NJ] = {};
    bf16x8 bP[2][NJ], bQ[2][NJ];

    auto STAGE = [&](char* dst, int tt) {
        const __bf16* ga = gA + (size_t)tt * 64;
        #pragma unroll
        for (int j = 0; j < CHA; ++j)
            async16(ga + (size_t)32 * K * j, dst + w * 1024 + j * 4096);
    };
    auto LOADB = [&](bf16x8 (&dst)[2][NJ], int tt) {
        const __bf16* gb = gB + (size_t)tt * 64;
        #pragma unroll
        for (int kh = 0; kh < 2; ++kh)
            #pragma unroll
            for (int j = 0; j < NJ; ++j)
                dst[kh][j] = *(const bf16x8*)(gb + (size_t)j * 16 * K + kh * 32);
    };
    auto COMPUTE = [&](const char* base, bf16x8 (&bf)[2][NJ]) {
        #pragma unroll
        for (int kh = 0; kh < 2; ++kh) {
            bf16x8 a[NI];
            #pragma unroll
            for (int i = 0; i < NI; ++i)
                a[i] = *(const bf16x8*)(base + (wm * WMR + i * 16 + lm) * 128
                                        + ((kh * 4 + lh) ^ axor) * 16);
            __builtin_amdgcn_s_setprio(1);
            #pragma unroll
            for (int i = 0; i < NI; ++i)
                #pragma unroll
                for (int j = 0; j < NJ; ++j)
                    acc[i][j] = __builtin_amdgcn_mfma_f32_16x16x32_bf16(
                        a[i], bf[kh][j], acc[i][j], 0, 0, 0);
            __builtin_amdgcn_s_setprio(0);
        }
    };

    char* a0 = smem;
    char* a1 = smem + ABYTES;
    char* a2 = smem + 2 * ABYTES;

    const int NT = K >> 6;
    STAGE(a0, 0);
    LOADB(bP, 0);
    STAGE(a1, 1);

    // invariant at pair start: a0=chunk tt, a1=tt+1, a2 free; bP=B(tt)
    for (int tt = 0; tt < NT - 2; tt += 2) {
        wait_vm_lgkm0<CHA>();                 // A(tt) + B(tt) landed
        __builtin_amdgcn_s_barrier();
        __builtin_amdgcn_sched_barrier(0);
        LOADB(bQ, tt + 1);
        STAGE(a2, tt + 2);
        __builtin_amdgcn_sched_barrier(0);
        COMPUTE(a0, bP);

        wait_vm_lgkm0<CHA>();                 // A(tt+1) + B(tt+1) landed
        __builtin_amdgcn_s_barrier();
        __builtin_amdgcn_sched_barrier(0);
        if (tt + 2 < NT - 2 || true) {}       // (kept simple: issues below)
        LOADB(bP, tt + 2);
        if (tt + 3 < NT) STAGE(a0, tt + 3);
        __builtin_amdgcn_sched_barrier(0);
        COMPUTE(a1, bQ);

        char* tmp = a0; a0 = a2; a2 = a1; a1 = tmp;  // (a0,a1,a2) <- (a2,a0,a1)
    }
    // final pair: a0=chunk NT-2, a1=NT-1, bP=B(NT-2)
    wait_vm_lgkm0<CHA>();
    __builtin_amdgcn_s_barrier();
    __builtin_amdgcn_sched_barrier(0);
    LOADB(bQ, NT - 1);
    __builtin_amdgcn_sched_barrier(0);
    COMPUTE(a0, bP);
    wait_vm_lgkm0<0>();
    __builtin_amdgcn_s_barrier();
    __builtin_amdgcn_sched_barrier(0);
    COMPUTE(a1, bQ);

    // epilogue
    #pragma unroll
    for (int i = 0; i < NI; ++i) {
        const int row0 = bm + wm * WMR + i * 16 + lh * 4;
        #pragma unroll
        for (int j = 0; j < NJ; ++j) {
            const int col = bn + wn * WNC + j * 16 + lm;
            const float bv = bias[col];
            #pragma unroll
            for (int r = 0; r < 4; ++r) {
                float v = acc[i][j][r] + bv;
                if (RELU) v = fmaxf(v, 0.f);
                C[(size_t)(row0 + r) * N + col] = (TOUT)v;
            }
        }
    }
}

// ---- fused fp32->bf16 casts (8 elems / thread) ----
__device__ __forceinline__ void cvt8(const float* __restrict__ src,
                                     __bf16* __restrict__ dst, int g) {
    const float4* p = reinterpret_cast<const float4*>(src) + (size_t)g * 2;
    float4 a = p[0], b = p[1];
    bf16x8 v;
    v[0] = (__bf16)a.x; v[1] = (__bf16)a.y; v[2] = (__bf16)a.z; v[3] = (__bf16)a.w;
    v[4] = (__bf16)b.x; v[5] = (__bf16)b.y; v[6] = (__bf16)b.z; v[7] = (__bf16)b.w;
    reinterpret_cast<bf16x8*>(dst)[g] = v;
}

__global__ __launch_bounds__(256) void cvt_pair(
    const float* __restrict__ s0, __bf16* __restrict__ d0, int n0,
    const float* __restrict__ s1, __bf16* __restrict__ d1)
{
    int i = blockIdx.x * 256 + threadIdx.x;
    if (i < n0) cvt8(s0, d0, i);
    else        cvt8(s1, d1, i - n0);
}

__global__ __launch_bounds__(256) void cvt_triple(
    const float* __restrict__ s0, __bf16* __restrict__ d0, int n0,
    const float* __restrict__ s1, __bf16* __restrict__ d1, int n1,
    const float* __restrict__ s2, __bf16* __restrict__ d2)
{
    int i = blockIdx.x * 256 + threadIdx.x;
    if (i < n0)           cvt8(s0, d0, i);
    else if (i < n0 + n1) cvt8(s1, d1, i - n0);
    else                  cvt8(s2, d2, i - n0 - n1);
}

// XOR-mask of initial qubits whose cos(theta) multiply into final <Z_q>.
__constant__ unsigned short kSMask[12] = {
    0xAAB, 0xFFD, 0xFFA, 0xFF5, 0xFEA, 0xFD5,
    0xFAA, 0xF55, 0xEAA, 0xD55, 0xAAA, 0x555
};

// Fused: z = h2 @ W3^T + b3 ; qz = masked cos-products ; h3 = relu(qz@dW1^T+db1)
__global__ __launch_bounds__(256) void enc3q_dec1(
    const float* __restrict__ H2,   // 2048 x 1024 (f32)
    const float* __restrict__ W3,   // 12 x 1024
    const float* __restrict__ b3,   // 12
    const float* __restrict__ qp,   // 12
    const float* __restrict__ dW1,  // 1024 x 12
    const float* __restrict__ db1,  // 1024
    __bf16* __restrict__ H3)        // 2048 x 1024 (bf16)
{
    const int b    = blockIdx.x;
    const int t    = threadIdx.x;
    const int lane = t & 63;
    const int wid  = t >> 6;

    float h[4];
    #pragma unroll
    for (int i = 0; i < 4; ++i) h[i] = H2[(size_t)b * 1024 + t + i * 256];

    __shared__ float wred[4][12];
    __shared__ float ctheta[12];
    __shared__ float qz[12];

    #pragma unroll 1
    for (int n = 0; n < 12; ++n) {
        float p = 0.f;
        #pragma unroll
        for (int i = 0; i < 4; ++i)
            p = fmaf(h[i], W3[n * 1024 + t + i * 256], p);
        #pragma unroll
        for (int off = 32; off > 0; off >>= 1)
            p += __shfl_down(p, off);
        if (lane == 0) wred[wid][n] = p;
    }
    __syncthreads();

    if (t < 12) {
        float z = wred[0][t] + wred[1][t] + wred[2][t] + wred[3][t]
                + b3[t] + qp[t];
        ctheta[t] = cosf(z);
    }
    __syncthreads();

    if (t < 12) {
        const unsigned m = kSMask[t];
        float prod = 1.f;
        #pragma unroll
        for (int j = 0; j < 12; ++j)
            if ((m >> j) & 1) prod *= ctheta[j];
        qz[t] = prod;
    }
    __syncthreads();

    bf16x4 v;
    #pragma unroll
    for (int j = 0; j < 4; ++j) {
        const int n = t * 4 + j;
        float acc = db1[n];
        #pragma unroll
        for (int k = 0; k < 12; ++k)
            acc = fmaf(qz[k], dW1[n * 12 + k], acc);
        v[j] = (__bf16)fmaxf(acc, 0.f);
    }
    *reinterpret_cast<bf16x4*>(&H3[(size_t)b * 1024 + t * 4]) = v;
}

extern "C" void kernel_launch(void* const* d_in, const int* in_sizes, int n_in,
                              void* d_out, int out_size, void* d_ws, size_t ws_size,
                              hipStream_t stream) {
    const float* x   = (const float*)d_in[0];
    const float* w1  = (const float*)d_in[1];
    const float* b1  = (const float*)d_in[2];
    const float* w2  = (const float*)d_in[3];
    const float* b2  = (const float*)d_in[4];
    const float* w3  = (const float*)d_in[5];
    const float* b3  = (const float*)d_in[6];
    const float* qp  = (const float*)d_in[7];
    const float* dw1 = (const float*)d_in[8];
    const float* db1 = (const float*)d_in[9];
    const float* dw2 = (const float*)d_in[10];
    const float* db2 = (const float*)d_in[11];
    const float* dw3 = (const float*)d_in[12];
    const float* db3 = (const float*)d_in[13];
    float* out = (float*)d_out;

    const int B = 2048, D = 4096, H1 = 2048, H2 = 1024;

    static int attr_done = 0;
    if (!attr_done) {
        hipFuncSetAttribute((const void*)&gemm_bdir<128, 128, __bf16, true>,
                            hipFuncAttributeMaxDynamicSharedMemorySize, 49152);
        hipFuncSetAttribute((const void*)&gemm_bdir<128, 64, float, true>,
                            hipFuncAttributeMaxDynamicSharedMemorySize, 49152);
        hipFuncSetAttribute((const void*)&gemm_bdir<256, 64, __bf16, true>,
                            hipFuncAttributeMaxDynamicSharedMemorySize, 98304);
        hipFuncSetAttribute((const void*)&gemm_bdir<256, 128, float, false>,
                            hipFuncAttributeMaxDynamicSharedMemorySize, 98304);
        attr_done = 1;
    }

    // Workspace layout (bytes), lifetimes disjoint; peak 40 MB.
    char* ws = (char*)d_ws;
    __bf16* xb   = (__bf16*)(ws);              //  0..16M   x (bf16), dies after enc1
    __bf16* dw3b = (__bf16*)(ws);              //  0..16M   reuses xb region
    __bf16* w1b  = (__bf16*)(ws + 16777216);   // 16..32M   dies after enc1
    float*  h2f  = (float*) (ws + 16777216);   // 16..24M   after enc1
    __bf16* w2b  = (__bf16*)(ws + 25165824);   // 24..28M   dies after enc2
    __bf16* h3b  = (__bf16*)(ws + 25165824);   // 24..28M   after enc2
    __bf16* dw2b = (__bf16*)(ws + 29360128);   // 28..32M
    __bf16* h1b  = (__bf16*)(ws + 33554432);   // 32..40M   dies after enc2
    __bf16* h4b  = (__bf16*)(ws + 33554432);   // 32..40M   after enc2

    dim3 blk(256);

    // casts for enc1 (x, w1)
    cvt_pair<<<dim3(8192), blk, 0, stream>>>(x, xb, 1048576, w1, w1b);

    // enc1: h1 = relu(x @ w1^T + b1)   [2048x2048x4096]  grid 16x16
    gemm_bdir<128, 128, __bf16, true><<<dim3(16, 16), blk, 49152, stream>>>(
        xb, w1b, b1, h1b, B, H1, D);

    // casts for the rest (w2, dw2, dw3)
    cvt_triple<<<dim3(6144), blk, 0, stream>>>(w2, w2b, 262144,
                                               dw2, dw2b, 262144,
                                               dw3, dw3b);

    // enc2: h2 = relu(h1 @ w2^T + b2) -> f32   [2048x1024x2048]  grid 16x16
    gemm_bdir<128, 64, float, true><<<dim3(16, 16), blk, 49152, stream>>>(
        h1b, w2b, b2, h2f, B, H2, H1);

    // enc3 + quantum latent + dec1
    enc3q_dec1<<<dim3(B), blk, 0, stream>>>(h2f, w3, b3, qp, dw1, db1, h3b);

    // dec2: h4 = relu(h3 @ dw2^T + db2)   [2048x2048x1024]  grid 32x8
    gemm_bdir<256, 64, __bf16, true><<<dim3(32, 8), blk, 98304, stream>>>(
        h3b, dw2b, db2, h4b, B, H1, H2);

    // dec3: out = h4 @ dw3^T + db3 -> f32   [2048x4096x2048]  grid 32x8
    gemm_bdir<256, 128, float, false><<<dim3(32, 8), blk, 98304, stream>>>(
        h4b, dw3b, db3, out, B, D, H1);
}

// Round 6
// 166.525 us; speedup vs baseline: 1.5394x; 1.5394x over previous
//
#include <hip/hip_runtime.h>
#include <hip/hip_bf16.h>

// ---------------------------------------------------------------------------
// HybridAutoEncoder on MI355X — bf16 MFMA, 3-buffer-ring GEMM, both operands
// LDS-staged (R5 post-mortem: B-direct-to-VGPR exposed L2 latency per chunk).
//
// gemm_ring<BM,BN>: BK=64, 4 waves (2x2), 3-buffer LDS ring, depth-2
// prefetch with counted vmcnt(L) (L = loads/tile/wave, never 0 mid-loop),
// ONE barrier per K-chunk (stage goes to the free buffer; no read-drain
// needed), XOR-swizzled LDS (pre-swizzled global source + swizzled ds_read),
// setprio(1) around MFMA cluster. All grids 16x16 = 256 wgs = 1 block/CU.
//
//   enc1: relu(x@W1^T+b1)    gemm_ring<128,128>  K=4096  LDS 96KB
//   enc2: relu(h1@W2^T+b2)   gemm_ring<128,64>   K=2048  LDS 72KB (f32 out)
//   enc3+quantum+dec1 fused  (analytic quantum latent)
//   dec2: relu(h3@dW2^T+db2) gemm_ring<128,128>  K=1024  LDS 96KB
//   dec3: h4@dW3^T+db3       gemm_ring<128,256>  K=2048  LDS 144KB (f32 out)
// ---------------------------------------------------------------------------

typedef __bf16 bf16x8 __attribute__((ext_vector_type(8)));
typedef __bf16 bf16x4 __attribute__((ext_vector_type(4)));
typedef float  f32x4  __attribute__((ext_vector_type(4)));

__device__ __forceinline__ void async16(const void* g, void* l) {
    __builtin_amdgcn_global_load_lds(
        (const __attribute__((address_space(1))) unsigned int*)g,
        (__attribute__((address_space(3))) unsigned int*)l,
        16, 0, 0);
}

template<int VM> __device__ __forceinline__ void wait_vm() {
    if constexpr (VM == 0)       asm volatile("s_waitcnt vmcnt(0) lgkmcnt(0)" ::: "memory");
    else if constexpr (VM == 6)  asm volatile("s_waitcnt vmcnt(6) lgkmcnt(0)" ::: "memory");
    else if constexpr (VM == 8)  asm volatile("s_waitcnt vmcnt(8) lgkmcnt(0)" ::: "memory");
    else if constexpr (VM == 12) asm volatile("s_waitcnt vmcnt(12) lgkmcnt(0)" ::: "memory");
    else static_assert(VM == 0 || VM == 6 || VM == 8 || VM == 12, "unsupported VM");
}

// C = act(A @ W^T + bias). A: MxK bf16 row-major. W: NxK bf16 row-major.
// K mult of 64, NT >= 3. Grid (N/BN, M/BM) (= 16x16 here).
// Dynamic LDS = 3*(BM+BN)*128 bytes.
template <int BM, int BN, typename TOUT, bool RELU>
__global__ __launch_bounds__(256) void gemm_ring(
    const __bf16* __restrict__ A, const __bf16* __restrict__ W,
    const float* __restrict__ bias, TOUT* __restrict__ C,
    int M, int N, int K)
{
    constexpr int CHA = BM / 32, CHB = BN / 32, L = CHA + CHB;
    constexpr int ABYTES = BM * 128, BUFB = (BM + BN) * 128;
    constexpr int WMR = BM / 2, WNC = BN / 2;
    constexpr int NI = WMR / 16, NJ = WNC / 16;

    extern __shared__ char smem[];

    const int t = threadIdx.x, lane = t & 63, w = t >> 6;

    // XCD-aware bijective swizzle (grid 16x16, 256 % 8 == 0), column-major
    // decode so each XCD owns contiguous bn-panels (weights stay L2-resident).
    const int gx = gridDim.x, gy = gridDim.y;
    const int lin = blockIdx.y * gx + blockIdx.x;
    const int cpx = (gx * gy) >> 3;
    const int swz = (lin & 7) * cpx + (lin >> 3);
    const int bm = (swz % gy) * BM;
    const int bn = (swz / gy) * BN;

    // staging: 8 lanes/row, XOR-swizzled source col-slot (both-sides rule 21)
    const int sr  = lane >> 3;
    const int scs = (lane & 7) ^ sr;
    const __bf16* gA = A + (size_t)(bm + w * 8 + sr) * K + scs * 8;
    const __bf16* gB = W + (size_t)(bn + w * 8 + sr) * K + scs * 8;

    // fragment decomposition
    const int lm = lane & 15, lh = lane >> 4;
    const int wm = w >> 1, wn = w & 1;
    const int axor = lm & 7;

    f32x4 acc[NI][NJ] = {};

    auto STAGE = [&](char* buf, int tt) {
        const __bf16* ga = gA + (size_t)tt * 64;
        const __bf16* gb = gB + (size_t)tt * 64;
        char* la = buf + w * 1024;
        char* lb = buf + ABYTES + w * 1024;
        #pragma unroll
        for (int j = 0; j < CHA; ++j) async16(ga + (size_t)32 * K * j, la + j * 4096);
        #pragma unroll
        for (int j = 0; j < CHB; ++j) async16(gb + (size_t)32 * K * j, lb + j * 4096);
    };

    auto COMPUTE = [&](const char* base) {
        #pragma unroll
        for (int kh = 0; kh < 2; ++kh) {
            const int sl = ((kh * 4 + lh) ^ axor) * 16;
            bf16x8 a[NI], b[NJ];
            #pragma unroll
            for (int i = 0; i < NI; ++i)
                a[i] = *(const bf16x8*)(base + (wm * WMR + i * 16 + lm) * 128 + sl);
            #pragma unroll
            for (int j = 0; j < NJ; ++j)
                b[j] = *(const bf16x8*)(base + ABYTES + (wn * WNC + j * 16 + lm) * 128 + sl);
            __builtin_amdgcn_s_setprio(1);
            #pragma unroll
            for (int i = 0; i < NI; ++i)
                #pragma unroll
                for (int j = 0; j < NJ; ++j)
                    acc[i][j] = __builtin_amdgcn_mfma_f32_16x16x32_bf16(
                        a[i], b[j], acc[i][j], 0, 0, 0);
            __builtin_amdgcn_s_setprio(0);
        }
    };

    const int NT = K >> 6;
    char* cur = smem;
    char* nxt = smem + BUFB;
    char* fre = smem + 2 * BUFB;

    STAGE(cur, 0);
    STAGE(nxt, 1);

    for (int tt = 0; tt < NT; ++tt) {
        if (tt < NT - 1) wait_vm<L>();   // tile tt landed; tt+1 (and tt+2) in flight
        else             wait_vm<0>();
        __builtin_amdgcn_s_barrier();
        __builtin_amdgcn_sched_barrier(0);
        if (tt + 2 < NT) STAGE(fre, tt + 2);
        __builtin_amdgcn_sched_barrier(0);
        COMPUTE(cur);
        char* tmp = cur; cur = nxt; nxt = fre; fre = tmp;
    }

    // epilogue
    #pragma unroll
    for (int i = 0; i < NI; ++i) {
        const int row0 = bm + wm * WMR + i * 16 + lh * 4;
        #pragma unroll
        for (int j = 0; j < NJ; ++j) {
            const int col = bn + wn * WNC + j * 16 + lm;
            const float bv = bias[col];
            #pragma unroll
            for (int r = 0; r < 4; ++r) {
                float v = acc[i][j][r] + bv;
                if (RELU) v = fmaxf(v, 0.f);
                C[(size_t)(row0 + r) * N + col] = (TOUT)v;
            }
        }
    }
}

// ---- fused fp32->bf16 casts (8 elems / thread) ----
__device__ __forceinline__ void cvt8(const float* __restrict__ src,
                                     __bf16* __restrict__ dst, int g) {
    const float4* p = reinterpret_cast<const float4*>(src) + (size_t)g * 2;
    float4 a = p[0], b = p[1];
    bf16x8 v;
    v[0] = (__bf16)a.x; v[1] = (__bf16)a.y; v[2] = (__bf16)a.z; v[3] = (__bf16)a.w;
    v[4] = (__bf16)b.x; v[5] = (__bf16)b.y; v[6] = (__bf16)b.z; v[7] = (__bf16)b.w;
    reinterpret_cast<bf16x8*>(dst)[g] = v;
}

__global__ __launch_bounds__(256) void cvt_pair(
    const float* __restrict__ s0, __bf16* __restrict__ d0, int n0,
    const float* __restrict__ s1, __bf16* __restrict__ d1)
{
    int i = blockIdx.x * 256 + threadIdx.x;
    if (i < n0) cvt8(s0, d0, i);
    else        cvt8(s1, d1, i - n0);
}

__global__ __launch_bounds__(256) void cvt_triple(
    const float* __restrict__ s0, __bf16* __restrict__ d0, int n0,
    const float* __restrict__ s1, __bf16* __restrict__ d1, int n1,
    const float* __restrict__ s2, __bf16* __restrict__ d2)
{
    int i = blockIdx.x * 256 + threadIdx.x;
    if (i < n0)           cvt8(s0, d0, i);
    else if (i < n0 + n1) cvt8(s1, d1, i - n0);
    else                  cvt8(s2, d2, i - n0 - n1);
}

// XOR-mask of initial qubits whose cos(theta) multiply into final <Z_q>.
__constant__ unsigned short kSMask[12] = {
    0xAAB, 0xFFD, 0xFFA, 0xFF5, 0xFEA, 0xFD5,
    0xFAA, 0xF55, 0xEAA, 0xD55, 0xAAA, 0x555
};

// Fused: z = h2 @ W3^T + b3 ; qz = masked cos-products ; h3 = relu(qz@dW1^T+db1)
__global__ __launch_bounds__(256) void enc3q_dec1(
    const float* __restrict__ H2,   // 2048 x 1024 (f32)
    const float* __restrict__ W3,   // 12 x 1024
    const float* __restrict__ b3,   // 12
    const float* __restrict__ qp,   // 12
    const float* __restrict__ dW1,  // 1024 x 12
    const float* __restrict__ db1,  // 1024
    __bf16* __restrict__ H3)        // 2048 x 1024 (bf16)
{
    const int b    = blockIdx.x;
    const int t    = threadIdx.x;
    const int lane = t & 63;
    const int wid  = t >> 6;

    float h[4];
    #pragma unroll
    for (int i = 0; i < 4; ++i) h[i] = H2[(size_t)b * 1024 + t + i * 256];

    __shared__ float wred[4][12];
    __shared__ float ctheta[12];
    __shared__ float qz[12];

    #pragma unroll 1
    for (int n = 0; n < 12; ++n) {
        float p = 0.f;
        #pragma unroll
        for (int i = 0; i < 4; ++i)
            p = fmaf(h[i], W3[n * 1024 + t + i * 256], p);
        #pragma unroll
        for (int off = 32; off > 0; off >>= 1)
            p += __shfl_down(p, off);
        if (lane == 0) wred[wid][n] = p;
    }
    __syncthreads();

    if (t < 12) {
        float z = wred[0][t] + wred[1][t] + wred[2][t] + wred[3][t]
                + b3[t] + qp[t];
        ctheta[t] = cosf(z);
    }
    __syncthreads();

    if (t < 12) {
        const unsigned m = kSMask[t];
        float prod = 1.f;
        #pragma unroll
        for (int j = 0; j < 12; ++j)
            if ((m >> j) & 1) prod *= ctheta[j];
        qz[t] = prod;
    }
    __syncthreads();

    bf16x4 v;
    #pragma unroll
    for (int j = 0; j < 4; ++j) {
        const int n = t * 4 + j;
        float acc = db1[n];
        #pragma unroll
        for (int k = 0; k < 12; ++k)
            acc = fmaf(qz[k], dW1[n * 12 + k], acc);
        v[j] = (__bf16)fmaxf(acc, 0.f);
    }
    *reinterpret_cast<bf16x4*>(&H3[(size_t)b * 1024 + t * 4]) = v;
}

extern "C" void kernel_launch(void* const* d_in, const int* in_sizes, int n_in,
                              void* d_out, int out_size, void* d_ws, size_t ws_size,
                              hipStream_t stream) {
    const float* x   = (const float*)d_in[0];
    const float* w1  = (const float*)d_in[1];
    const float* b1  = (const float*)d_in[2];
    const float* w2  = (const float*)d_in[3];
    const float* b2  = (const float*)d_in[4];
    const float* w3  = (const float*)d_in[5];
    const float* b3  = (const float*)d_in[6];
    const float* qp  = (const float*)d_in[7];
    const float* dw1 = (const float*)d_in[8];
    const float* db1 = (const float*)d_in[9];
    const float* dw2 = (const float*)d_in[10];
    const float* db2 = (const float*)d_in[11];
    const float* dw3 = (const float*)d_in[12];
    const float* db3 = (const float*)d_in[13];
    float* out = (float*)d_out;

    const int B = 2048, D = 4096, H1 = 2048, H2 = 1024;

    static int attr_done = 0;
    if (!attr_done) {
        hipFuncSetAttribute((const void*)&gemm_ring<128, 128, __bf16, true>,
                            hipFuncAttributeMaxDynamicSharedMemorySize, 98304);
        hipFuncSetAttribute((const void*)&gemm_ring<128, 64, float, true>,
                            hipFuncAttributeMaxDynamicSharedMemorySize, 73728);
        hipFuncSetAttribute((const void*)&gemm_ring<128, 256, float, false>,
                            hipFuncAttributeMaxDynamicSharedMemorySize, 147456);
        attr_done = 1;
    }

    // Workspace layout (bytes), lifetimes disjoint; peak 40 MB.
    char* ws = (char*)d_ws;
    __bf16* xb   = (__bf16*)(ws);              //  0..16M   x (bf16), dies after enc1
    __bf16* dw3b = (__bf16*)(ws);              //  0..16M   reuses xb region
    __bf16* w1b  = (__bf16*)(ws + 16777216);   // 16..32M   dies after enc1
    float*  h2f  = (float*) (ws + 16777216);   // 16..24M   after enc1
    __bf16* w2b  = (__bf16*)(ws + 25165824);   // 24..28M   dies after enc2
    __bf16* h3b  = (__bf16*)(ws + 25165824);   // 24..28M   after enc2
    __bf16* dw2b = (__bf16*)(ws + 29360128);   // 28..32M
    __bf16* h1b  = (__bf16*)(ws + 33554432);   // 32..40M   dies after enc2
    __bf16* h4b  = (__bf16*)(ws + 33554432);   // 32..40M   after enc2

    dim3 blk(256);
    dim3 grid16(16, 16);

    // casts for enc1 (x, w1)
    cvt_pair<<<dim3(8192), blk, 0, stream>>>(x, xb, 1048576, w1, w1b);

    // enc1: h1 = relu(x @ w1^T + b1)   [2048x2048x4096]
    gemm_ring<128, 128, __bf16, true><<<grid16, blk, 98304, stream>>>(
        xb, w1b, b1, h1b, B, H1, D);

    // casts for the rest (w2, dw2, dw3)
    cvt_triple<<<dim3(6144), blk, 0, stream>>>(w2, w2b, 262144,
                                               dw2, dw2b, 262144,
                                               dw3, dw3b);

    // enc2: h2 = relu(h1 @ w2^T + b2) -> f32   [2048x1024x2048]
    gemm_ring<128, 64, float, true><<<grid16, blk, 73728, stream>>>(
        h1b, w2b, b2, h2f, B, H2, H1);

    // enc3 + quantum latent + dec1
    enc3q_dec1<<<dim3(B), blk, 0, stream>>>(h2f, w3, b3, qp, dw1, db1, h3b);

    // dec2: h4 = relu(h3 @ dw2^T + db2)   [2048x2048x1024]
    gemm_ring<128, 128, __bf16, true><<<grid16, blk, 98304, stream>>>(
        h3b, dw2b, db2, h4b, B, H1, H2);

    // dec3: out = h4 @ dw3^T + db3 -> f32   [2048x4096x2048]
    gemm_ring<128, 256, float, false><<<grid16, blk, 147456, stream>>>(
        h4b, dw3b, db3, out, B, D, H1);
}

// Round 7
// 164.714 us; speedup vs baseline: 1.5563x; 1.0110x over previous
//
#include <hip/hip_runtime.h>
#include <hip/hip_bf16.h>

// ---------------------------------------------------------------------------
// HybridAutoEncoder on MI355X — bf16 MFMA GEMM, 3-buffer ring + 2 blocks/CU.
//
// R6 post-mortem: ring @1 block/CU regressed (no co-resident block to cover
// vmcnt stalls). R4 showed 2 blocks/CU (desync) is worth more than barrier
// count. This round: ring-3 (ONE barrier/chunk) at tile sizes whose LDS
// (3 bufs) fits TWO blocks per CU, with grids >= 512 wgs:
//
//   enc1: relu(x@W1^T+b1)    ring<128,64>  grid 32x16=512  72KB  K=4096
//   enc2: relu(h1@W2^T+b2)   ring<64,64>   grid 16x32=512  48KB  K=2048 (f32)
//   enc3+quantum+dec1 fused  (analytic quantum latent)
//   dec2: relu(h3@dW2^T+db2) ring<128,64>  grid 32x16=512  72KB  K=1024
//   dec3: h4@dW3^T+db3       ring<128,64>  grid 64x16=1024 72KB  K=2048 (f32)
//
// Ring: BK=64, depth-2 prefetch, counted vmcnt(L) (never 0 mid-loop), one
// s_barrier per chunk, XOR-swizzled LDS (pre-swizzled global source +
// swizzled ds_read), setprio(1) around MFMA cluster, XCD-aware swizzle.
// ---------------------------------------------------------------------------

typedef __bf16 bf16x8 __attribute__((ext_vector_type(8)));
typedef __bf16 bf16x4 __attribute__((ext_vector_type(4)));
typedef float  f32x4  __attribute__((ext_vector_type(4)));

__device__ __forceinline__ void async16(const void* g, void* l) {
    __builtin_amdgcn_global_load_lds(
        (const __attribute__((address_space(1))) unsigned int*)g,
        (__attribute__((address_space(3))) unsigned int*)l,
        16, 0, 0);
}

template<int VM> __device__ __forceinline__ void wait_vm() {
    if constexpr (VM == 0)      asm volatile("s_waitcnt vmcnt(0) lgkmcnt(0)" ::: "memory");
    else if constexpr (VM == 4) asm volatile("s_waitcnt vmcnt(4) lgkmcnt(0)" ::: "memory");
    else if constexpr (VM == 6) asm volatile("s_waitcnt vmcnt(6) lgkmcnt(0)" ::: "memory");
    else if constexpr (VM == 8) asm volatile("s_waitcnt vmcnt(8) lgkmcnt(0)" ::: "memory");
    else static_assert(VM == 0 || VM == 4 || VM == 6 || VM == 8, "unsupported VM");
}

// C = act(A @ W^T + bias). A: MxK bf16 row-major. W: NxK bf16 row-major.
// K mult of 64, NT >= 2. Grid (N/BN, M/BM), product divisible by 8.
// Dynamic LDS = 3*(BM+BN)*128 bytes.
template <int BM, int BN, typename TOUT, bool RELU>
__global__ __launch_bounds__(256) void gemm_ring(
    const __bf16* __restrict__ A, const __bf16* __restrict__ W,
    const float* __restrict__ bias, TOUT* __restrict__ C,
    int M, int N, int K)
{
    constexpr int CHA = BM / 32, CHB = BN / 32, L = CHA + CHB;
    constexpr int ABYTES = BM * 128, BUFB = (BM + BN) * 128;
    constexpr int WMR = BM / 2, WNC = BN / 2;
    constexpr int NI = WMR / 16, NJ = WNC / 16;

    extern __shared__ char smem[];

    const int t = threadIdx.x, lane = t & 63, w = t >> 6;

    // XCD-aware bijective swizzle (grid product % 8 == 0), column-major
    // decode so each XCD owns contiguous bn-panels (weights L2-resident).
    const int gx = gridDim.x, gy = gridDim.y;
    const int lin = blockIdx.y * gx + blockIdx.x;
    const int cpx = (gx * gy) >> 3;
    const int swz = (lin & 7) * cpx + (lin >> 3);
    const int bm = (swz % gy) * BM;
    const int bn = (swz / gy) * BN;

    // staging: 8 lanes/row, XOR-swizzled source col-slot (both-sides rule 21)
    const int sr  = lane >> 3;
    const int scs = (lane & 7) ^ sr;
    const __bf16* gA = A + (size_t)(bm + w * 8 + sr) * K + scs * 8;
    const __bf16* gB = W + (size_t)(bn + w * 8 + sr) * K + scs * 8;

    // fragment decomposition
    const int lm = lane & 15, lh = lane >> 4;
    const int wm = w >> 1, wn = w & 1;
    const int axor = lm & 7;

    f32x4 acc[NI][NJ] = {};

    auto STAGE = [&](char* buf, int tt) {
        const __bf16* ga = gA + (size_t)tt * 64;
        const __bf16* gb = gB + (size_t)tt * 64;
        char* la = buf + w * 1024;
        char* lb = buf + ABYTES + w * 1024;
        #pragma unroll
        for (int j = 0; j < CHA; ++j) async16(ga + (size_t)32 * K * j, la + j * 4096);
        #pragma unroll
        for (int j = 0; j < CHB; ++j) async16(gb + (size_t)32 * K * j, lb + j * 4096);
    };

    auto COMPUTE = [&](const char* base) {
        #pragma unroll
        for (int kh = 0; kh < 2; ++kh) {
            const int sl = ((kh * 4 + lh) ^ axor) * 16;
            bf16x8 a[NI], b[NJ];
            #pragma unroll
            for (int i = 0; i < NI; ++i)
                a[i] = *(const bf16x8*)(base + (wm * WMR + i * 16 + lm) * 128 + sl);
            #pragma unroll
            for (int j = 0; j < NJ; ++j)
                b[j] = *(const bf16x8*)(base + ABYTES + (wn * WNC + j * 16 + lm) * 128 + sl);
            __builtin_amdgcn_s_setprio(1);
            #pragma unroll
            for (int i = 0; i < NI; ++i)
                #pragma unroll
                for (int j = 0; j < NJ; ++j)
                    acc[i][j] = __builtin_amdgcn_mfma_f32_16x16x32_bf16(
                        a[i], b[j], acc[i][j], 0, 0, 0);
            __builtin_amdgcn_s_setprio(0);
        }
    };

    const int NT = K >> 6;
    char* cur = smem;
    char* nxt = smem + BUFB;
    char* fre = smem + 2 * BUFB;

    STAGE(cur, 0);
    STAGE(nxt, 1);

    for (int tt = 0; tt < NT; ++tt) {
        if (tt < NT - 1) wait_vm<L>();   // tile tt landed; tt+1 (and tt+2) in flight
        else             wait_vm<0>();
        __builtin_amdgcn_s_barrier();
        __builtin_amdgcn_sched_barrier(0);
        if (tt + 2 < NT) STAGE(fre, tt + 2);
        __builtin_amdgcn_sched_barrier(0);
        COMPUTE(cur);
        char* tmp = cur; cur = nxt; nxt = fre; fre = tmp;
    }

    // epilogue
    #pragma unroll
    for (int i = 0; i < NI; ++i) {
        const int row0 = bm + wm * WMR + i * 16 + lh * 4;
        #pragma unroll
        for (int j = 0; j < NJ; ++j) {
            const int col = bn + wn * WNC + j * 16 + lm;
            const float bv = bias[col];
            #pragma unroll
            for (int r = 0; r < 4; ++r) {
                float v = acc[i][j][r] + bv;
                if (RELU) v = fmaxf(v, 0.f);
                C[(size_t)(row0 + r) * N + col] = (TOUT)v;
            }
        }
    }
}

// ---- fused fp32->bf16 casts (8 elems / thread) ----
__device__ __forceinline__ void cvt8(const float* __restrict__ src,
                                     __bf16* __restrict__ dst, int g) {
    const float4* p = reinterpret_cast<const float4*>(src) + (size_t)g * 2;
    float4 a = p[0], b = p[1];
    bf16x8 v;
    v[0] = (__bf16)a.x; v[1] = (__bf16)a.y; v[2] = (__bf16)a.z; v[3] = (__bf16)a.w;
    v[4] = (__bf16)b.x; v[5] = (__bf16)b.y; v[6] = (__bf16)b.z; v[7] = (__bf16)b.w;
    reinterpret_cast<bf16x8*>(dst)[g] = v;
}

__global__ __launch_bounds__(256) void cvt_pair(
    const float* __restrict__ s0, __bf16* __restrict__ d0, int n0,
    const float* __restrict__ s1, __bf16* __restrict__ d1)
{
    int i = blockIdx.x * 256 + threadIdx.x;
    if (i < n0) cvt8(s0, d0, i);
    else        cvt8(s1, d1, i - n0);
}

__global__ __launch_bounds__(256) void cvt_triple(
    const float* __restrict__ s0, __bf16* __restrict__ d0, int n0,
    const float* __restrict__ s1, __bf16* __restrict__ d1, int n1,
    const float* __restrict__ s2, __bf16* __restrict__ d2)
{
    int i = blockIdx.x * 256 + threadIdx.x;
    if (i < n0)           cvt8(s0, d0, i);
    else if (i < n0 + n1) cvt8(s1, d1, i - n0);
    else                  cvt8(s2, d2, i - n0 - n1);
}

// XOR-mask of initial qubits whose cos(theta) multiply into final <Z_q>.
__constant__ unsigned short kSMask[12] = {
    0xAAB, 0xFFD, 0xFFA, 0xFF5, 0xFEA, 0xFD5,
    0xFAA, 0xF55, 0xEAA, 0xD55, 0xAAA, 0x555
};

// Fused: z = h2 @ W3^T + b3 ; qz = masked cos-products ; h3 = relu(qz@dW1^T+db1)
__global__ __launch_bounds__(256) void enc3q_dec1(
    const float* __restrict__ H2,   // 2048 x 1024 (f32)
    const float* __restrict__ W3,   // 12 x 1024
    const float* __restrict__ b3,   // 12
    const float* __restrict__ qp,   // 12
    const float* __restrict__ dW1,  // 1024 x 12
    const float* __restrict__ db1,  // 1024
    __bf16* __restrict__ H3)        // 2048 x 1024 (bf16)
{
    const int b    = blockIdx.x;
    const int t    = threadIdx.x;
    const int lane = t & 63;
    const int wid  = t >> 6;

    float h[4];
    #pragma unroll
    for (int i = 0; i < 4; ++i) h[i] = H2[(size_t)b * 1024 + t + i * 256];

    __shared__ float wred[4][12];
    __shared__ float ctheta[12];
    __shared__ float qz[12];

    #pragma unroll 1
    for (int n = 0; n < 12; ++n) {
        float p = 0.f;
        #pragma unroll
        for (int i = 0; i < 4; ++i)
            p = fmaf(h[i], W3[n * 1024 + t + i * 256], p);
        #pragma unroll
        for (int off = 32; off > 0; off >>= 1)
            p += __shfl_down(p, off);
        if (lane == 0) wred[wid][n] = p;
    }
    __syncthreads();

    if (t < 12) {
        float z = wred[0][t] + wred[1][t] + wred[2][t] + wred[3][t]
                + b3[t] + qp[t];
        ctheta[t] = cosf(z);
    }
    __syncthreads();

    if (t < 12) {
        const unsigned m = kSMask[t];
        float prod = 1.f;
        #pragma unroll
        for (int j = 0; j < 12; ++j)
            if ((m >> j) & 1) prod *= ctheta[j];
        qz[t] = prod;
    }
    __syncthreads();

    bf16x4 v;
    #pragma unroll
    for (int j = 0; j < 4; ++j) {
        const int n = t * 4 + j;
        float acc = db1[n];
        #pragma unroll
        for (int k = 0; k < 12; ++k)
            acc = fmaf(qz[k], dW1[n * 12 + k], acc);
        v[j] = (__bf16)fmaxf(acc, 0.f);
    }
    *reinterpret_cast<bf16x4*>(&H3[(size_t)b * 1024 + t * 4]) = v;
}

extern "C" void kernel_launch(void* const* d_in, const int* in_sizes, int n_in,
                              void* d_out, int out_size, void* d_ws, size_t ws_size,
                              hipStream_t stream) {
    const float* x   = (const float*)d_in[0];
    const float* w1  = (const float*)d_in[1];
    const float* b1  = (const float*)d_in[2];
    const float* w2  = (const float*)d_in[3];
    const float* b2  = (const float*)d_in[4];
    const float* w3  = (const float*)d_in[5];
    const float* b3  = (const float*)d_in[6];
    const float* qp  = (const float*)d_in[7];
    const float* dw1 = (const float*)d_in[8];
    const float* db1 = (const float*)d_in[9];
    const float* dw2 = (const float*)d_in[10];
    const float* db2 = (const float*)d_in[11];
    const float* dw3 = (const float*)d_in[12];
    const float* db3 = (const float*)d_in[13];
    float* out = (float*)d_out;

    const int B = 2048, D = 4096, H1 = 2048, H2 = 1024;

    static int attr_done = 0;
    if (!attr_done) {
        hipFuncSetAttribute((const void*)&gemm_ring<128, 64, __bf16, true>,
                            hipFuncAttributeMaxDynamicSharedMemorySize, 73728);
        hipFuncSetAttribute((const void*)&gemm_ring<64, 64, float, true>,
                            hipFuncAttributeMaxDynamicSharedMemorySize, 49152);
        hipFuncSetAttribute((const void*)&gemm_ring<128, 64, float, false>,
                            hipFuncAttributeMaxDynamicSharedMemorySize, 73728);
        attr_done = 1;
    }

    // Workspace layout (bytes), lifetimes disjoint; peak 40 MB.
    char* ws = (char*)d_ws;
    __bf16* xb   = (__bf16*)(ws);              //  0..16M   x (bf16), dies after enc1
    __bf16* dw3b = (__bf16*)(ws);              //  0..16M   reuses xb region
    __bf16* w1b  = (__bf16*)(ws + 16777216);   // 16..32M   dies after enc1
    float*  h2f  = (float*) (ws + 16777216);   // 16..24M   after enc1
    __bf16* w2b  = (__bf16*)(ws + 25165824);   // 24..28M   dies after enc2
    __bf16* h3b  = (__bf16*)(ws + 25165824);   // 24..28M   after enc2
    __bf16* dw2b = (__bf16*)(ws + 29360128);   // 28..32M
    __bf16* h1b  = (__bf16*)(ws + 33554432);   // 32..40M   dies after enc2
    __bf16* h4b  = (__bf16*)(ws + 33554432);   // 32..40M   after enc2

    dim3 blk(256);

    // casts for enc1 (x, w1)
    cvt_pair<<<dim3(8192), blk, 0, stream>>>(x, xb, 1048576, w1, w1b);

    // enc1: h1 = relu(x @ w1^T + b1)   [2048x2048x4096]  grid 32x16 = 512
    gemm_ring<128, 64, __bf16, true><<<dim3(32, 16), blk, 73728, stream>>>(
        xb, w1b, b1, h1b, B, H1, D);

    // casts for the rest (w2, dw2, dw3)
    cvt_triple<<<dim3(6144), blk, 0, stream>>>(w2, w2b, 262144,
                                               dw2, dw2b, 262144,
                                               dw3, dw3b);

    // enc2: h2 = relu(h1 @ w2^T + b2) -> f32   [2048x1024x2048]  grid 16x32 = 512
    gemm_ring<64, 64, float, true><<<dim3(16, 32), blk, 49152, stream>>>(
        h1b, w2b, b2, h2f, B, H2, H1);

    // enc3 + quantum latent + dec1
    enc3q_dec1<<<dim3(B), blk, 0, stream>>>(h2f, w3, b3, qp, dw1, db1, h3b);

    // dec2: h4 = relu(h3 @ dw2^T + db2)   [2048x2048x1024]  grid 32x16 = 512
    gemm_ring<128, 64, __bf16, true><<<dim3(32, 16), blk, 73728, stream>>>(
        h3b, dw2b, db2, h4b, B, H1, H2);

    // dec3: out = h4 @ dw3^T + db3 -> f32   [2048x4096x2048]  grid 64x16 = 1024
    gemm_ring<128, 64, float, false><<<dim3(64, 16), blk, 73728, stream>>>(
        h4b, dw3b, db3, out, B, D, H1);
}

// Round 9
// 156.467 us; speedup vs baseline: 1.6383x; 1.0527x over previous
//
#include <hip/hip_runtime.h>
#include <hip/hip_bf16.h>

// ---------------------------------------------------------------------------
// HybridAutoEncoder on MI355X — bf16 MFMA dbuf GEMM (R4 structure) +
// cast-hiding with a RACE-FREE workspace layout.
//
// R8 post-mortem: tail-cast destinations (w2b/dw2b) aliased w1b, which the
// concurrent enc1 GEMM was reading -> corruption. This round every buffer
// live during the enc1 launch has a disjoint region (64 MB total); if
// ws_size < 64 MB we fall back to the serial-cast path (R4, proven).
//
//   cvt_pair(x,w1)                                    [serial, BW-bound]
//   enc1: relu(x@W1^T+b1)  gemm<128,64> 512 blks + 256 cast-tail blks
//   enc2: relu(h1@W2^T+b2) gemm<64,64>  512 blks     (f32 out)
//   enc3+quantum+dec1 fused (analytic latent: qz = masked cos-products)
//   dec2: relu(h3@dW2^T+db2) gemm<128,64>  512 blks
//   dec3: h4@dW3^T+db3       gemm<128,128> 512 blks  (f32 out)
// ---------------------------------------------------------------------------

typedef __bf16 bf16x8 __attribute__((ext_vector_type(8)));
typedef __bf16 bf16x4 __attribute__((ext_vector_type(4)));
typedef float  f32x4  __attribute__((ext_vector_type(4)));

__device__ __forceinline__ void async16(const void* g, void* l) {
    __builtin_amdgcn_global_load_lds(
        (const __attribute__((address_space(1))) unsigned int*)g,
        (__attribute__((address_space(3))) unsigned int*)l,
        16, 0, 0);
}

template<int VM> __device__ __forceinline__ void wait_vm() {
    if constexpr (VM == 0)      asm volatile("s_waitcnt vmcnt(0) lgkmcnt(0)" ::: "memory");
    else if constexpr (VM == 4) asm volatile("s_waitcnt vmcnt(4) lgkmcnt(0)" ::: "memory");
    else if constexpr (VM == 6) asm volatile("s_waitcnt vmcnt(6) lgkmcnt(0)" ::: "memory");
    else if constexpr (VM == 8) asm volatile("s_waitcnt vmcnt(8) lgkmcnt(0)" ::: "memory");
    else static_assert(VM == 0 || VM == 4 || VM == 6 || VM == 8, "unsupported VM");
}

__device__ __forceinline__ void cvt8(const float* __restrict__ src,
                                     __bf16* __restrict__ dst, int g) {
    const float4* p = reinterpret_cast<const float4*>(src) + (size_t)g * 2;
    float4 a = p[0], b = p[1];
    bf16x8 v;
    v[0] = (__bf16)a.x; v[1] = (__bf16)a.y; v[2] = (__bf16)a.z; v[3] = (__bf16)a.w;
    v[4] = (__bf16)b.x; v[5] = (__bf16)b.y; v[6] = (__bf16)b.z; v[7] = (__bf16)b.w;
    reinterpret_cast<bf16x8*>(dst)[g] = v;
}

// C = act(A @ W^T + bias). A: MxK bf16 row-major. W: NxK bf16 row-major.
// 1D grid: GX*GY gemm blocks (+256 cast-tail blocks if TAIL).
// Dynamic LDS = 2*(BM+BN)*128 bytes.
template <int BM, int BN, int GX, int GY, typename TOUT, bool RELU, bool TAIL>
__global__ __launch_bounds__(256) void gemm_pipe(
    const __bf16* __restrict__ A, const __bf16* __restrict__ W,
    const float* __restrict__ bias, TOUT* __restrict__ C,
    int M, int N, int K,
    const float* __restrict__ cs0, __bf16* __restrict__ cd0, int cn0,
    const float* __restrict__ cs1, __bf16* __restrict__ cd1, int cn1,
    const float* __restrict__ cs2, __bf16* __restrict__ cd2, int cn2)
{
    constexpr int CHA = BM / 32, CHB = BN / 32, L = CHA + CHB;
    constexpr int ABYTES = BM * 128, BUFB = (BM + BN) * 128;
    constexpr int WMR = BM / 2, WNC = BN / 2;
    constexpr int NI = WMR / 16, NJ = WNC / 16;

    extern __shared__ char smem[];

    const int lin = blockIdx.x;

    if (TAIL && lin >= GX * GY) {
        // ---- cast tail: grid-stride f32->bf16 over 3 tensors ----
        const int total = cn0 + cn1 + cn2;
        const int nthr  = 256 * 256;
        for (int g = (lin - GX * GY) * 256 + threadIdx.x; g < total; g += nthr) {
            if (g < cn0)            cvt8(cs0, cd0, g);
            else if (g < cn0 + cn1) cvt8(cs1, cd1, g - cn0);
            else                    cvt8(cs2, cd2, g - cn0 - cn1);
        }
        return;
    }

    const int t = threadIdx.x, lane = t & 63, w = t >> 6;

    // XCD-aware bijective swizzle (GX*GY % 8 == 0); column-major decode so
    // each XCD owns contiguous bn-panels (weights stay L2-resident).
    constexpr int CPX = (GX * GY) >> 3;
    const int swz = (lin & 7) * CPX + (lin >> 3);
    const int bm = (swz % GY) * BM;
    const int bn = (swz / GY) * BN;

    // staging: 8 lanes/row, XOR-swizzled source col-slot (both-sides rule 21)
    const int sr  = lane >> 3;
    const int scs = (lane & 7) ^ sr;
    const __bf16* gA = A + (size_t)(bm + w * 8 + sr) * K + scs * 8;
    const __bf16* gB = W + (size_t)(bn + w * 8 + sr) * K + scs * 8;

    // fragment decomposition
    const int lm = lane & 15, lh = lane >> 4;
    const int wm = w >> 1, wn = w & 1;
    const int axor = lm & 7;

    f32x4 acc[NI][NJ] = {};

    auto STAGE = [&](int buf, int tt) {
        char* la = smem + buf * BUFB + w * 1024;
        char* lb = smem + buf * BUFB + ABYTES + w * 1024;
        const __bf16* ga = gA + (size_t)tt * 64;
        const __bf16* gb = gB + (size_t)tt * 64;
        #pragma unroll
        for (int j = 0; j < CHA; ++j) async16(ga + (size_t)32 * K * j, la + j * 4096);
        #pragma unroll
        for (int j = 0; j < CHB; ++j) async16(gb + (size_t)32 * K * j, lb + j * 4096);
    };

    auto COMPUTE = [&](int buf) {
        const char* base = smem + buf * BUFB;
        #pragma unroll
        for (int kh = 0; kh < 2; ++kh) {
            const int sl = ((kh * 4 + lh) ^ axor) * 16;
            bf16x8 a[NI], b[NJ];
            #pragma unroll
            for (int i = 0; i < NI; ++i)
                a[i] = *(const bf16x8*)(base + (wm * WMR + i * 16 + lm) * 128 + sl);
            #pragma unroll
            for (int j = 0; j < NJ; ++j)
                b[j] = *(const bf16x8*)(base + ABYTES + (wn * WNC + j * 16 + lm) * 128 + sl);
            __builtin_amdgcn_s_setprio(1);
            #pragma unroll
            for (int i = 0; i < NI; ++i)
                #pragma unroll
                for (int j = 0; j < NJ; ++j)
                    acc[i][j] = __builtin_amdgcn_mfma_f32_16x16x32_bf16(
                        a[i], b[j], acc[i][j], 0, 0, 0);
            __builtin_amdgcn_s_setprio(0);
        }
    };

    const int NT = K >> 6;
    STAGE(0, 0);
    STAGE(1, 1);

    for (int tt = 0; tt < NT; ++tt) {
        if (tt < NT - 1) wait_vm<L>();
        else             wait_vm<0>();
        __builtin_amdgcn_s_barrier();
        __builtin_amdgcn_sched_barrier(0);
        COMPUTE(tt & 1);
        if (tt + 2 < NT) {
            asm volatile("s_waitcnt lgkmcnt(0)" ::: "memory");
            __builtin_amdgcn_s_barrier();
            __builtin_amdgcn_sched_barrier(0);
            STAGE(tt & 1, tt + 2);
        }
    }

    // epilogue
    #pragma unroll
    for (int i = 0; i < NI; ++i) {
        const int row0 = bm + wm * WMR + i * 16 + lh * 4;
        #pragma unroll
        for (int j = 0; j < NJ; ++j) {
            const int col = bn + wn * WNC + j * 16 + lm;
            const float bv = bias[col];
            #pragma unroll
            for (int r = 0; r < 4; ++r) {
                float v = acc[i][j][r] + bv;
                if (RELU) v = fmaxf(v, 0.f);
                C[(size_t)(row0 + r) * N + col] = (TOUT)v;
            }
        }
    }
}

__global__ __launch_bounds__(256) void cvt_pair(
    const float* __restrict__ s0, __bf16* __restrict__ d0, int n0,
    const float* __restrict__ s1, __bf16* __restrict__ d1)
{
    int i = blockIdx.x * 256 + threadIdx.x;
    if (i < n0) cvt8(s0, d0, i);
    else        cvt8(s1, d1, i - n0);
}

__global__ __launch_bounds__(256) void cvt_triple(
    const float* __restrict__ s0, __bf16* __restrict__ d0, int n0,
    const float* __restrict__ s1, __bf16* __restrict__ d1, int n1,
    const float* __restrict__ s2, __bf16* __restrict__ d2)
{
    int i = blockIdx.x * 256 + threadIdx.x;
    if (i < n0)           cvt8(s0, d0, i);
    else if (i < n0 + n1) cvt8(s1, d1, i - n0);
    else                  cvt8(s2, d2, i - n0 - n1);
}

// XOR-mask of initial qubits whose cos(theta) multiply into final <Z_q>.
__constant__ unsigned short kSMask[12] = {
    0xAAB, 0xFFD, 0xFFA, 0xFF5, 0xFEA, 0xFD5,
    0xFAA, 0xF55, 0xEAA, 0xD55, 0xAAA, 0x555
};

// Fused: z = h2 @ W3^T + b3 ; qz = masked cos-products ; h3 = relu(qz@dW1^T+db1)
__global__ __launch_bounds__(256) void enc3q_dec1(
    const float* __restrict__ H2,   // 2048 x 1024 (f32)
    const float* __restrict__ W3,   // 12 x 1024
    const float* __restrict__ b3,   // 12
    const float* __restrict__ qp,   // 12
    const float* __restrict__ dW1,  // 1024 x 12
    const float* __restrict__ db1,  // 1024
    __bf16* __restrict__ H3)        // 2048 x 1024 (bf16)
{
    const int b    = blockIdx.x;
    const int t    = threadIdx.x;
    const int lane = t & 63;
    const int wid  = t >> 6;

    float h[4];
    #pragma unroll
    for (int i = 0; i < 4; ++i) h[i] = H2[(size_t)b * 1024 + t + i * 256];

    __shared__ float wred[4][12];
    __shared__ float ctheta[12];
    __shared__ float qz[12];

    #pragma unroll 1
    for (int n = 0; n < 12; ++n) {
        float p = 0.f;
        #pragma unroll
        for (int i = 0; i < 4; ++i)
            p = fmaf(h[i], W3[n * 1024 + t + i * 256], p);
        #pragma unroll
        for (int off = 32; off > 0; off >>= 1)
            p += __shfl_down(p, off);
        if (lane == 0) wred[wid][n] = p;
    }
    __syncthreads();

    if (t < 12) {
        float z = wred[0][t] + wred[1][t] + wred[2][t] + wred[3][t]
                + b3[t] + qp[t];
        ctheta[t] = cosf(z);
    }
    __syncthreads();

    if (t < 12) {
        const unsigned m = kSMask[t];
        float prod = 1.f;
        #pragma unroll
        for (int j = 0; j < 12; ++j)
            if ((m >> j) & 1) prod *= ctheta[j];
        qz[t] = prod;
    }
    __syncthreads();

    bf16x4 v;
    #pragma unroll
    for (int j = 0; j < 4; ++j) {
        const int n = t * 4 + j;
        float acc = db1[n];
        #pragma unroll
        for (int k = 0; k < 12; ++k)
            acc = fmaf(qz[k], dW1[n * 12 + k], acc);
        v[j] = (__bf16)fmaxf(acc, 0.f);
    }
    *reinterpret_cast<bf16x4*>(&H3[(size_t)b * 1024 + t * 4]) = v;
}

extern "C" void kernel_launch(void* const* d_in, const int* in_sizes, int n_in,
                              void* d_out, int out_size, void* d_ws, size_t ws_size,
                              hipStream_t stream) {
    const float* x   = (const float*)d_in[0];
    const float* w1  = (const float*)d_in[1];
    const float* b1  = (const float*)d_in[2];
    const float* w2  = (const float*)d_in[3];
    const float* b2  = (const float*)d_in[4];
    const float* w3  = (const float*)d_in[5];
    const float* b3  = (const float*)d_in[6];
    const float* qp  = (const float*)d_in[7];
    const float* dw1 = (const float*)d_in[8];
    const float* db1 = (const float*)d_in[9];
    const float* dw2 = (const float*)d_in[10];
    const float* db2 = (const float*)d_in[11];
    const float* dw3 = (const float*)d_in[12];
    const float* db3 = (const float*)d_in[13];
    float* out = (float*)d_out;

    const int B = 2048, D = 4096, H1 = 2048, H2 = 1024;

    static int attr_done = 0;
    if (!attr_done) {
        hipFuncSetAttribute((const void*)&gemm_pipe<128, 64, 32, 16, __bf16, true, true>,
                            hipFuncAttributeMaxDynamicSharedMemorySize, 49152);
        hipFuncSetAttribute((const void*)&gemm_pipe<128, 64, 32, 16, __bf16, true, false>,
                            hipFuncAttributeMaxDynamicSharedMemorySize, 49152);
        hipFuncSetAttribute((const void*)&gemm_pipe<64, 64, 16, 32, float, true, false>,
                            hipFuncAttributeMaxDynamicSharedMemorySize, 32768);
        hipFuncSetAttribute((const void*)&gemm_pipe<128, 128, 32, 16, float, false, false>,
                            hipFuncAttributeMaxDynamicSharedMemorySize, 65536);
        attr_done = 1;
    }

    dim3 blk(256);
    char* ws = (char*)d_ws;

    if (ws_size >= (size_t)67108864) {
        // ------------- concurrent layout: ALL regions disjoint -------------
        // Live during enc1 launch (GEMM reads xb,w1b; writes h1b; tail
        // writes w2b,dw2b,dw3b — no overlap anywhere):
        __bf16* xb   = (__bf16*)(ws);              //  0      .. 16.78M
        __bf16* w1b  = (__bf16*)(ws + 16777216);   // 16.78M  .. 33.55M
        __bf16* h1b  = (__bf16*)(ws + 33554432);   // 33.55M  .. 41.94M
        __bf16* w2b  = (__bf16*)(ws + 41943040);   // 41.94M  .. 46.14M
        __bf16* dw2b = (__bf16*)(ws + 46137344);   // 46.14M  .. 50.33M
        __bf16* dw3b = (__bf16*)(ws + 50331648);   // 50.33M  .. 67.11M
        // After enc1, xb/w1b are dead; reuse for activations:
        float*  h2f  = (float*) (ws);              //  0      ..  8.39M
        __bf16* h3b  = (__bf16*)(ws + 8388608);    //  8.39M  .. 12.58M
        __bf16* h4b  = (__bf16*)(ws + 16777216);   // 16.78M  .. 25.17M

        // serial casts for enc1 inputs (x, w1)
        cvt_pair<<<dim3(8192), blk, 0, stream>>>(x, xb, 1048576, w1, w1b);

        // enc1 GEMM (512 blocks) + cast tail (256 blocks: w2, dw2, dw3)
        gemm_pipe<128, 64, 32, 16, __bf16, true, true><<<dim3(768), blk, 49152, stream>>>(
            xb, w1b, b1, h1b, B, H1, D,
            w2, w2b, 262144, dw2, dw2b, 262144, dw3, dw3b, 1048576);

        // enc2 -> f32
        gemm_pipe<64, 64, 16, 32, float, true, false><<<dim3(512), blk, 32768, stream>>>(
            h1b, w2b, b2, h2f, B, H2, H1,
            nullptr, nullptr, 0, nullptr, nullptr, 0, nullptr, nullptr, 0);

        enc3q_dec1<<<dim3(B), blk, 0, stream>>>(h2f, w3, b3, qp, dw1, db1, h3b);

        gemm_pipe<128, 64, 32, 16, __bf16, true, false><<<dim3(512), blk, 49152, stream>>>(
            h3b, dw2b, db2, h4b, B, H1, H2,
            nullptr, nullptr, 0, nullptr, nullptr, 0, nullptr, nullptr, 0);

        gemm_pipe<128, 128, 32, 16, float, false, false><<<dim3(512), blk, 65536, stream>>>(
            h4b, dw3b, db3, out, B, D, H1,
            nullptr, nullptr, 0, nullptr, nullptr, 0, nullptr, nullptr, 0);
    } else {
        // ------------- fallback: R4 serial-cast layout (40 MB, proven) -----
        __bf16* xb   = (__bf16*)(ws);              //  0..16M   dies after enc1
        __bf16* dw3b = (__bf16*)(ws);              //  0..16M   reuses xb region
        __bf16* w1b  = (__bf16*)(ws + 16777216);   // 16..32M   dies after enc1
        float*  h2f  = (float*) (ws + 16777216);   // 16..24M   after enc1
        __bf16* w2b  = (__bf16*)(ws + 25165824);   // 24..28M   dies after enc2
        __bf16* h3b  = (__bf16*)(ws + 25165824);   // 24..28M   after enc2
        __bf16* dw2b = (__bf16*)(ws + 29360128);   // 28..32M
        __bf16* h1b  = (__bf16*)(ws + 33554432);   // 32..40M   dies after enc2
        __bf16* h4b  = (__bf16*)(ws + 33554432);   // 32..40M   after enc2

        cvt_pair<<<dim3(8192), blk, 0, stream>>>(x, xb, 1048576, w1, w1b);

        gemm_pipe<128, 64, 32, 16, __bf16, true, false><<<dim3(512), blk, 49152, stream>>>(
            xb, w1b, b1, h1b, B, H1, D,
            nullptr, nullptr, 0, nullptr, nullptr, 0, nullptr, nullptr, 0);

        cvt_triple<<<dim3(6144), blk, 0, stream>>>(w2, w2b, 262144,
                                                   dw2, dw2b, 262144,
                                                   dw3, dw3b);

        gemm_pipe<64, 64, 16, 32, float, true, false><<<dim3(512), blk, 32768, stream>>>(
            h1b, w2b, b2, h2f, B, H2, H1,
            nullptr, nullptr, 0, nullptr, nullptr, 0, nullptr, nullptr, 0);

        enc3q_dec1<<<dim3(B), blk, 0, stream>>>(h2f, w3, b3, qp, dw1, db1, h3b);

        gemm_pipe<128, 64, 32, 16, __bf16, true, false><<<dim3(512), blk, 49152, stream>>>(
            h3b, dw2b, db2, h4b, B, H1, H2,
            nullptr, nullptr, 0, nullptr, nullptr, 0, nullptr, nullptr, 0);

        gemm_pipe<128, 128, 32, 16, float, false, false><<<dim3(512), blk, 65536, stream>>>(
            h4b, dw3b, db3, out, B, D, H1,
            nullptr, nullptr, 0, nullptr, nullptr, 0, nullptr, nullptr, 0);
    }
}